// Round 4
// baseline (372.630 us; speedup 1.0000x reference)
//
#include <hip/hip_runtime.h>
#include <stdint.h>

// SFFM — inputs [L=4,B=8,C=256,H=64,W=64] float32, W [256,256] float32.
//   gap    = mean(inputs, axis=(3,4))             -> [L,B,C]
//   scores = gap @ W^T                            -> [L,B,C]
//   attn   = softmax over L                       -> [L,B,C]
//   out    = inputs * attn[:,:,:,None,None]
//
// v4: SINGLE kernel with a MANUAL device-scope grid barrier.
// R3's cooperative launch silently failed (output stayed zero — absmax
// 1.39 ≈ max|in|*attn). Cooperative launch + graph capture don't mix, so
// the grid sync is now hand-rolled: __threadfence + agent-scope atomic
// arrive/spin. The barrier counter lives in the (poisoned) workspace and
// is zeroed by a 4-byte hipMemsetAsync before the kernel each iteration.
//
// 1024 persistent blocks (exactly 4/CU x 256 CU; residency forced by
// __launch_bounds__(256,4) which caps VGPR at 128 — this kernel is far
// below). Each block owns 2 (b,d) pairs = 8 channels:
//   phase 1: GAP of its 8 channels (wave w <-> layer w, wave-reduce only)
//   grid barrier
//   phase 2: per pair, dot gap rows with W[d,:], softmax over L,
//            stream-scale the SAME 8 channels (L3-warm from phase 1;
//            128 MiB input < 256 MiB LLC). nt-stores protect the LLC.
//
// Channel index: ch = (l*B + b)*C + d.

#define L_DIM 4
#define B_DIM 8
#define C_DIM 256
#define HW    4096                      // 64*64 per channel
#define F4_PER_CH (HW / 4)              // 1024 float4 per channel
#define NCH   (L_DIM * B_DIM * C_DIM)   // 8192 channels
#define GRID_BLOCKS 1024                // 4 blocks/CU x 256 CU — co-resident
#define PAIRS 2                         // (b,d) pairs per block

typedef float nfloat4 __attribute__((ext_vector_type(4)));  // for nt-store

__global__ __launch_bounds__(256, 4) void sffm_fused(
        const float4* __restrict__ in, const float* __restrict__ Wf,
        float* __restrict__ gap, unsigned* __restrict__ bar,
        float4* __restrict__ out) {
    const int t    = threadIdx.x;
    const int wave = t >> 6;            // 4 waves; wave w handles layer w
    const int lane = t & 63;

    // ---- Phase 1: GAP for this block's 2 pairs x 4 layers (1 layer/wave).
    #pragma unroll
    for (int p = 0; p < PAIRS; ++p) {
        const int bid = blockIdx.x * PAIRS + p;     // b*C + d
        const int d   = bid & (C_DIM - 1);
        const int b   = bid >> 8;
        const int ch  = ((wave * B_DIM + b) << 8) + d;
        const float4* base = in + (size_t)ch * F4_PER_CH;
        float s = 0.0f;
        #pragma unroll
        for (int k = 0; k < 16; ++k) {              // 1024 f4 / 64 lanes
            float4 v = base[lane + k * 64];
            s += (v.x + v.y) + (v.z + v.w);
        }
        #pragma unroll
        for (int off = 32; off > 0; off >>= 1)
            s += __shfl_down(s, off, 64);
        if (lane == 0) gap[ch] = s * (1.0f / (float)HW);
    }

    // ---- Manual grid barrier (device scope; works under graph capture).
    __syncthreads();                    // all waves' gap stores drained to L2
    if (t == 0) {
        __threadfence();                // release: write back to coherent point
        __hip_atomic_fetch_add(bar, 1u, __ATOMIC_RELAXED,
                               __HIP_MEMORY_SCOPE_AGENT);
        while (__hip_atomic_load(bar, __ATOMIC_RELAXED,
                                 __HIP_MEMORY_SCOPE_AGENT) < GRID_BLOCKS) {}
        __threadfence();                // acquire: invalidate stale cache lines
    }
    __syncthreads();                    // block observes barrier completion

    // ---- Phase 2: attention + stream-scale.
    __shared__ float part[4][4];        // [wave][l']
    __shared__ float a_s[4];

    for (int p = 0; p < PAIRS; ++p) {
        const int bid = blockIdx.x * PAIRS + p;
        const int d   = bid & (C_DIM - 1);
        const int b   = bid >> 8;

        // scores[l] = dot(gap[l,b,:], W[d,:]) — thread t holds column t
        const float wv = Wf[(size_t)d * C_DIM + t];
        float p0 = gap[(0 * B_DIM + b) * C_DIM + t] * wv;
        float p1 = gap[(1 * B_DIM + b) * C_DIM + t] * wv;
        float p2 = gap[(2 * B_DIM + b) * C_DIM + t] * wv;
        float p3 = gap[(3 * B_DIM + b) * C_DIM + t] * wv;
        #pragma unroll
        for (int off = 32; off > 0; off >>= 1) {
            p0 += __shfl_down(p0, off, 64);
            p1 += __shfl_down(p1, off, 64);
            p2 += __shfl_down(p2, off, 64);
            p3 += __shfl_down(p3, off, 64);
        }
        if (lane == 0) {
            part[wave][0] = p0; part[wave][1] = p1;
            part[wave][2] = p2; part[wave][3] = p3;
        }
        __syncthreads();
        if (t < 4) {
            const float s0 = part[0][0] + part[1][0] + part[2][0] + part[3][0];
            const float s1 = part[0][1] + part[1][1] + part[2][1] + part[3][1];
            const float s2 = part[0][2] + part[1][2] + part[2][2] + part[3][2];
            const float s3 = part[0][3] + part[1][3] + part[2][3] + part[3][3];
            const float m  = fmaxf(fmaxf(s0, s1), fmaxf(s2, s3));
            const float e0 = __expf(s0 - m), e1 = __expf(s1 - m);
            const float e2 = __expf(s2 - m), e3 = __expf(s3 - m);
            const float inv = 1.0f / (e0 + e1 + e2 + e3);
            const float el  = (t == 0) ? e0 : (t == 1) ? e1 : (t == 2) ? e2 : e3;
            a_s[t] = el * inv;
        }
        __syncthreads();
        const float a0 = a_s[0], a1 = a_s[1], a2 = a_s[2], a3 = a_s[3];

        // stream-scale the 4 channels of this pair (L3-warm from phase 1)
        #pragma unroll
        for (int l = 0; l < L_DIM; ++l) {
            const float a = (l == 0) ? a0 : (l == 1) ? a1 : (l == 2) ? a2 : a3;
            const int ch = ((l * B_DIM + b) << 8) + d;
            const float4* src = in + (size_t)ch * F4_PER_CH;
            nfloat4*      dst = (nfloat4*)(out + (size_t)ch * F4_PER_CH);
            #pragma unroll
            for (int k = 0; k < 4; ++k) {
                float4 v = src[t + k * 256];
                nfloat4 q = { v.x * a, v.y * a, v.z * a, v.w * a };
                __builtin_nontemporal_store(q, &dst[t + k * 256]);
            }
        }
        // iter p+1's part[] writes happen only after every thread passed
        // iter p's second __syncthreads, which follows all part[]/a_s reads.
    }
}

extern "C" void kernel_launch(void* const* d_in, const int* in_sizes, int n_in,
                              void* d_out, int out_size, void* d_ws, size_t ws_size,
                              hipStream_t stream) {
    const float4* in_p  = (const float4*)d_in[0];
    const float*  W_p   = (const float*)d_in[1];
    float4*       out_p = (float4*)d_out;
    float*        gap   = (float*)d_ws;                 // 8192 floats
    unsigned*     bar   = (unsigned*)((char*)d_ws + NCH * sizeof(float));

    // workspace is poisoned each iteration — zero the barrier counter
    hipMemsetAsync((void*)bar, 0, sizeof(unsigned), stream);

    sffm_fused<<<GRID_BLOCKS, 256, 0, stream>>>(in_p, W_p, gap, bar, out_p);
}

// Round 5
// 313.219 us; speedup vs baseline: 1.1897x; 1.1897x over previous
//
#include <hip/hip_runtime.h>
#include <stdint.h>

// SFFM — inputs [L=4,B=8,C=256,H=64,W=64] float32, W [256,256] float32.
//   gap    = mean(inputs, axis=(3,4))             -> [L,B,C]
//   scores = gap @ W^T                            -> [L,B,C]
//   attn   = softmax over L                       -> [L,B,C]
//   out    = inputs * attn[:,:,:,None,None]
//
// v5: single kernel, TREE grid barrier. R4's flat barrier (1024 RMWs +
// 1024 tight-loop pollers on ONE line) serialized at the coherence point:
// kernel ran 216 µs at 1.25 TB/s with perfect traffic (FETCH=WRITE=131 MB)
// and VALUBusy 1.4% — pure stall. Fix: 16 padded leaf counters (64
// arrivals each) -> root (16 RMWs) -> broadcast to 16 padded go-flags;
// each block polls only its group's flag with s_sleep backoff.
// Everything else identical to R4 (fence recipe proven correct there).
//
// 1024 blocks = 4/CU x 256 CU, residency forced by __launch_bounds__(256,4)
// (48 VGPR measured in R4 — far under the 128 cap). Each block: 2 (b,d)
// pairs = 8 channels. Phase 1 GAP (wave w <-> layer w), barrier, phase 2
// attn + stream-scale of the same 8 channels (L3-warm; nt-stores protect).
//
// Channel index: ch = (l*B + b)*C + d.

#define L_DIM 4
#define B_DIM 8
#define C_DIM 256
#define HW    4096
#define F4_PER_CH (HW / 4)
#define NCH   (L_DIM * B_DIM * C_DIM)   // 8192
#define GRID_BLOCKS 1024
#define PAIRS 2
#define NLEAF 16                        // 1024 blocks / 64 per leaf
// sync[] layout (uints): leaf[i] at i*16 (i<16), root at 256, go[i] at 272+i*16
#define SYNC_ROOT 256
#define SYNC_GO   272
#define SYNC_UINTS (SYNC_GO + NLEAF * 16)   // 528 uints

typedef float nfloat4 __attribute__((ext_vector_type(4)));  // for nt-store

__global__ __launch_bounds__(256, 4) void sffm_fused(
        const float4* __restrict__ in, const float* __restrict__ Wf,
        float* __restrict__ gap, unsigned* __restrict__ sync,
        float4* __restrict__ out) {
    const int t    = threadIdx.x;
    const int wave = t >> 6;            // wave w handles layer w
    const int lane = t & 63;

    // ---- Phase 1: GAP for this block's 2 pairs x 4 layers (1 layer/wave).
    #pragma unroll
    for (int p = 0; p < PAIRS; ++p) {
        const int bid = blockIdx.x * PAIRS + p;     // b*C + d
        const int d   = bid & (C_DIM - 1);
        const int b   = bid >> 8;
        const int ch  = ((wave * B_DIM + b) << 8) + d;
        const float4* base = in + (size_t)ch * F4_PER_CH;
        float s = 0.0f;
        #pragma unroll
        for (int k = 0; k < 16; ++k) {              // 1024 f4 / 64 lanes
            float4 v = base[lane + k * 64];
            s += (v.x + v.y) + (v.z + v.w);
        }
        #pragma unroll
        for (int off = 32; off > 0; off >>= 1)
            s += __shfl_down(s, off, 64);
        if (lane == 0) gap[ch] = s * (1.0f / (float)HW);
    }

    // ---- Tree grid barrier (device scope; graph-capture safe).
    __syncthreads();
    if (t == 0) {
        __threadfence();                            // release gap[] stores
        const int g = blockIdx.x >> 6;              // leaf group, 64 blocks
        const unsigned a = __hip_atomic_fetch_add(&sync[g * 16], 1u,
                               __ATOMIC_RELAXED, __HIP_MEMORY_SCOPE_AGENT);
        if (a == 63u) {                             // last arrival in leaf
            const unsigned r = __hip_atomic_fetch_add(&sync[SYNC_ROOT], 1u,
                                   __ATOMIC_RELAXED, __HIP_MEMORY_SCOPE_AGENT);
            if (r == NLEAF - 1u) {                  // last leaf -> broadcast
                __threadfence();
                #pragma unroll
                for (int i = 0; i < NLEAF; ++i)
                    __hip_atomic_store(&sync[SYNC_GO + i * 16], 1u,
                                       __ATOMIC_RELAXED,
                                       __HIP_MEMORY_SCOPE_AGENT);
            }
        }
        while (__hip_atomic_load(&sync[SYNC_GO + g * 16], __ATOMIC_RELAXED,
                                 __HIP_MEMORY_SCOPE_AGENT) == 0u)
            __builtin_amdgcn_s_sleep(16);           // ~1024 cyc backoff
        __threadfence();                            // acquire
    }
    __syncthreads();

    // ---- Phase 2: attention + stream-scale.
    __shared__ float part[4][4];        // [wave][l']
    __shared__ float a_s[4];

    for (int p = 0; p < PAIRS; ++p) {
        const int bid = blockIdx.x * PAIRS + p;
        const int d   = bid & (C_DIM - 1);
        const int b   = bid >> 8;

        // scores[l] = dot(gap[l,b,:], W[d,:]) — thread t holds column t
        const float wv = Wf[(size_t)d * C_DIM + t];
        float p0 = gap[(0 * B_DIM + b) * C_DIM + t] * wv;
        float p1 = gap[(1 * B_DIM + b) * C_DIM + t] * wv;
        float p2 = gap[(2 * B_DIM + b) * C_DIM + t] * wv;
        float p3 = gap[(3 * B_DIM + b) * C_DIM + t] * wv;
        #pragma unroll
        for (int off = 32; off > 0; off >>= 1) {
            p0 += __shfl_down(p0, off, 64);
            p1 += __shfl_down(p1, off, 64);
            p2 += __shfl_down(p2, off, 64);
            p3 += __shfl_down(p3, off, 64);
        }
        if (lane == 0) {
            part[wave][0] = p0; part[wave][1] = p1;
            part[wave][2] = p2; part[wave][3] = p3;
        }
        __syncthreads();
        if (t < 4) {
            const float s0 = part[0][0] + part[1][0] + part[2][0] + part[3][0];
            const float s1 = part[0][1] + part[1][1] + part[2][1] + part[3][1];
            const float s2 = part[0][2] + part[1][2] + part[2][2] + part[3][2];
            const float s3 = part[0][3] + part[1][3] + part[2][3] + part[3][3];
            const float m  = fmaxf(fmaxf(s0, s1), fmaxf(s2, s3));
            const float e0 = __expf(s0 - m), e1 = __expf(s1 - m);
            const float e2 = __expf(s2 - m), e3 = __expf(s3 - m);
            const float inv = 1.0f / (e0 + e1 + e2 + e3);
            const float el  = (t == 0) ? e0 : (t == 1) ? e1 : (t == 2) ? e2 : e3;
            a_s[t] = el * inv;
        }
        __syncthreads();
        const float a0 = a_s[0], a1 = a_s[1], a2 = a_s[2], a3 = a_s[3];

        // stream-scale the 4 channels of this pair (L3-warm from phase 1)
        #pragma unroll
        for (int l = 0; l < L_DIM; ++l) {
            const float a = (l == 0) ? a0 : (l == 1) ? a1 : (l == 2) ? a2 : a3;
            const int ch = ((l * B_DIM + b) << 8) + d;
            const float4* src = in + (size_t)ch * F4_PER_CH;
            nfloat4*      dst = (nfloat4*)(out + (size_t)ch * F4_PER_CH);
            #pragma unroll
            for (int k = 0; k < 4; ++k) {
                float4 v = src[t + k * 256];
                nfloat4 q = { v.x * a, v.y * a, v.z * a, v.w * a };
                __builtin_nontemporal_store(q, &dst[t + k * 256]);
            }
        }
        // iter p+1's part[] writes happen only after every thread passed
        // iter p's second __syncthreads (which follows all part[]/a_s reads).
    }
}

extern "C" void kernel_launch(void* const* d_in, const int* in_sizes, int n_in,
                              void* d_out, int out_size, void* d_ws, size_t ws_size,
                              hipStream_t stream) {
    const float4* in_p  = (const float4*)d_in[0];
    const float*  W_p   = (const float*)d_in[1];
    float4*       out_p = (float4*)d_out;
    float*        gap   = (float*)d_ws;                          // 8192 floats
    unsigned*     sync  = (unsigned*)((char*)d_ws + NCH * sizeof(float));

    // workspace is poisoned each iteration — zero the sync area
    hipMemsetAsync((void*)sync, 0, SYNC_UINTS * sizeof(unsigned), stream);

    sffm_fused<<<GRID_BLOCKS, 256, 0, stream>>>(in_p, W_p, gap, sync, out_p);
}

// Round 6
// 248.370 us; speedup vs baseline: 1.5003x; 1.2611x over previous
//
#include <hip/hip_runtime.h>
#include <stdint.h>

// SFFM — inputs [L=4,B=8,C=256,H=64,W=64] float32, W [256,256] float32.
//   gap    = mean(inputs, axis=(3,4))             -> [L,B,C]
//   scores = gap @ W^T                            -> [L,B,C]
//   attn   = softmax over L                       -> [L,B,C]
//   out    = inputs * attn[:,:,:,None,None]
//
// v6: back to the 3-kernel split (fused+grid-barrier measured 157 µs of
// kernel time vs ~93 µs for the split — barrier convoy cost >> the two
// launch boundaries it removed). This round's lever: the STREAMER, the
// only kernel off its roofline (was ~67 µs = 3.9 TB/s mixed vs 6.3
// ceiling). Rewritten persistent-style: 2048 blocks (8/CU -> full 32-wave
// occupancy), each owns 4 channels, processed as channel-PAIRS with all
// 8 float4 loads issued before any store (2x MLP, 8x less block churn
// than the old 8192-short-block version).
//   K1 GAP:   8192 blocks, proven ~21 µs = 6.2 TB/s (at ceiling) — unchanged
//   K2 attn:  2048 blocks, ~4 µs — unchanged
//   K3 scale: persistent streamer, nt-stores (counter-proven to keep the
//             input L3-resident: fused FETCH was 131 MB, not 262)
//
// Channel index: ch = (l*B + b)*C + d.

#define L_DIM 4
#define B_DIM 8
#define C_DIM 256
#define HW    4096                      // 64*64 per channel
#define F4_PER_CH (HW / 4)              // 1024 float4 per channel
#define NCH   (L_DIM * B_DIM * C_DIM)   // 8192 channels
#define NBD   (B_DIM * C_DIM)           // 2048 (b,d) pairs
#define SCALE_BLOCKS 2048               // 8 blocks/CU
#define CH_PER_BLOCK (NCH / SCALE_BLOCKS)   // 4

typedef float nfloat4 __attribute__((ext_vector_type(4)));  // for nt-store

// ---- Kernel 1: GAP. One block (256 threads) per channel. ----
__global__ __launch_bounds__(256) void gap_kernel(
        const float4* __restrict__ in, float* __restrict__ gap) {
    const int ch = blockIdx.x;
    const float4* base = in + (size_t)ch * F4_PER_CH;
    float s = 0.0f;
    #pragma unroll
    for (int k = 0; k < 4; ++k) {
        float4 p = base[threadIdx.x + k * 256];
        s += (p.x + p.y) + (p.z + p.w);
    }
    #pragma unroll
    for (int off = 32; off > 0; off >>= 1)
        s += __shfl_down(s, off, 64);
    __shared__ float wsum[4];
    const int wave = threadIdx.x >> 6;
    const int lane = threadIdx.x & 63;
    if (lane == 0) wsum[wave] = s;
    __syncthreads();
    if (threadIdx.x == 0) {
        gap[ch] = (wsum[0] + wsum[1] + wsum[2] + wsum[3]) * (1.0f / (float)HW);
    }
}

// ---- Kernel 2: attention. One block per (b,d); writes attn for all 4 l. ----
__global__ __launch_bounds__(256) void attn_kernel(
        const float* __restrict__ gap, const float* __restrict__ Wf,
        float* __restrict__ attn) {
    const int bid = blockIdx.x;          // b*C + d
    const int d   = bid & (C_DIM - 1);
    const int b   = bid >> 8;
    const int c   = threadIdx.x;

    const float w = Wf[(size_t)d * C_DIM + c];          // coalesced row read
    float p0 = gap[(0 * B_DIM + b) * C_DIM + c] * w;
    float p1 = gap[(1 * B_DIM + b) * C_DIM + c] * w;
    float p2 = gap[(2 * B_DIM + b) * C_DIM + c] * w;
    float p3 = gap[(3 * B_DIM + b) * C_DIM + c] * w;

    #pragma unroll
    for (int off = 32; off > 0; off >>= 1) {
        p0 += __shfl_down(p0, off, 64);
        p1 += __shfl_down(p1, off, 64);
        p2 += __shfl_down(p2, off, 64);
        p3 += __shfl_down(p3, off, 64);
    }
    __shared__ float part[4][4];   // [wave][l']
    const int wave = threadIdx.x >> 6;
    const int lane = threadIdx.x & 63;
    if (lane == 0) {
        part[wave][0] = p0; part[wave][1] = p1;
        part[wave][2] = p2; part[wave][3] = p3;
    }
    __syncthreads();
    if (threadIdx.x < 4) {
        const float s0 = part[0][0] + part[1][0] + part[2][0] + part[3][0];
        const float s1 = part[0][1] + part[1][1] + part[2][1] + part[3][1];
        const float s2 = part[0][2] + part[1][2] + part[2][2] + part[3][2];
        const float s3 = part[0][3] + part[1][3] + part[2][3] + part[3][3];
        const float m  = fmaxf(fmaxf(s0, s1), fmaxf(s2, s3));
        const float e0 = __expf(s0 - m), e1 = __expf(s1 - m);
        const float e2 = __expf(s2 - m), e3 = __expf(s3 - m);
        const float inv = 1.0f / (e0 + e1 + e2 + e3);
        const int   l   = threadIdx.x;
        const float el  = (l == 0) ? e0 : (l == 1) ? e1 : (l == 2) ? e2 : e3;
        attn[(l * B_DIM + b) * C_DIM + d] = el * inv;
    }
}

// ---- Kernel 3: persistent streamer. 2048 blocks x 4 channels each. ----
// Channel-pair inner step: issue all 8 float4 loads, then scale+store 8.
__global__ __launch_bounds__(256) void scale_kernel(
        const float4* __restrict__ in, const float* __restrict__ attn,
        float4* __restrict__ out) {
    const int t   = threadIdx.x;
    const int ch0 = blockIdx.x * CH_PER_BLOCK;
    #pragma unroll
    for (int cc = 0; cc < CH_PER_BLOCK; cc += 2) {
        const int chA = ch0 + cc;
        const int chB = ch0 + cc + 1;
        const float aA = attn[chA];      // uniform -> scalar broadcast
        const float aB = attn[chB];
        const float4* sA = in + (size_t)chA * F4_PER_CH;
        const float4* sB = in + (size_t)chB * F4_PER_CH;
        float4 vA[4], vB[4];
        #pragma unroll
        for (int k = 0; k < 4; ++k) vA[k] = sA[t + k * 256];
        #pragma unroll
        for (int k = 0; k < 4; ++k) vB[k] = sB[t + k * 256];
        nfloat4* dA = (nfloat4*)(out + (size_t)chA * F4_PER_CH);
        nfloat4* dB = (nfloat4*)(out + (size_t)chB * F4_PER_CH);
        #pragma unroll
        for (int k = 0; k < 4; ++k) {
            nfloat4 q = { vA[k].x * aA, vA[k].y * aA, vA[k].z * aA, vA[k].w * aA };
            __builtin_nontemporal_store(q, &dA[t + k * 256]);
        }
        #pragma unroll
        for (int k = 0; k < 4; ++k) {
            nfloat4 q = { vB[k].x * aB, vB[k].y * aB, vB[k].z * aB, vB[k].w * aB };
            __builtin_nontemporal_store(q, &dB[t + k * 256]);
        }
    }
}

extern "C" void kernel_launch(void* const* d_in, const int* in_sizes, int n_in,
                              void* d_out, int out_size, void* d_ws, size_t ws_size,
                              hipStream_t stream) {
    const float4* in_p  = (const float4*)d_in[0];
    const float*  W_p   = (const float*)d_in[1];
    float4*       out_p = (float4*)d_out;

    float* gap  = (float*)d_ws;                  // 8192 floats
    float* attn = (float*)d_ws + NCH;            // 8192 floats

    gap_kernel  <<<NCH, 256, 0, stream>>>(in_p, gap);
    attn_kernel <<<NBD, 256, 0, stream>>>(gap, W_p, attn);
    scale_kernel<<<SCALE_BLOCKS, 256, 0, stream>>>(in_p, attn, out_p);
}